// Round 2
// baseline (227.725 us; speedup 1.0000x reference)
//
#include <hip/hip_runtime.h>

// RoI bilinear pooling.
// img : (1, H=200, W=200, C=256) fp32, NHWC  -> channel vectors contiguous (1 KiB)
// rois: (1, N=2000, 4) fp32 (integer-valued x,y,w,h)
// out : (1, N, ps, ps, C) fp32
//
// R2: spatial sort pre-pass. RoIs are random in index order, so cross-roi
// pixel reuse (the remaining 2.5x read amplification, FETCH 158 MB vs 41 MB
// image) never hits L2. Pre-pass sorts roi indices by Morton code of the roi
// center (bitonic, one block, ~5 us); main kernel uses chunked XCD mapping
// (bid%8 == XCD on MI355X) so each XCD processes a contiguous run of
// spatially-sorted rois -> sliding working set per L2 is a few rois << 4 MB.
// Output still lands in the original roi slot (49 KiB contiguous per block).
//
// Main kernel (ps==7, C==256): one BLOCK per roi (7 waves), one WAVE per
// pooled row. Lane owns one float4 of the 256-channel vector. px loop fully
// unrolled -> 28 loads in flight per wave. Non-temporal output stores.

typedef float vfloat4 __attribute__((ext_vector_type(4)));

// ---- pre-pass: bitonic sort of (morton(center) << 11 | idx), n = 2048 ----

__global__ __launch_bounds__(256) void RoIPool_sort_kernel(
    const float* __restrict__ rois, int N, unsigned* __restrict__ perm)
{
    constexpr int n = 2048;            // pow2 >= N (host guards N <= 2048)
    __shared__ unsigned keys[n];
    const int t = threadIdx.x;

    for (int i = t; i < n; i += 256) {
        unsigned v = 0xFFFFFFFFu;      // pad sorts to the end
        if (i < N) {
            const float4 r = reinterpret_cast<const float4*>(rois)[i];
            int cx = (int)r.x + ((int)r.z >> 1);
            int cy = (int)r.y + ((int)r.w >> 1);
            cx = min(max(cx, 0), 255);
            cy = min(max(cy, 0), 255);
            unsigned mx = (unsigned)cx, my = (unsigned)cy;
            mx = (mx | (mx << 4)) & 0x0F0Fu;
            mx = (mx | (mx << 2)) & 0x3333u;
            mx = (mx | (mx << 1)) & 0x5555u;
            my = (my | (my << 4)) & 0x0F0Fu;
            my = (my | (my << 2)) & 0x3333u;
            my = (my | (my << 1)) & 0x5555u;
            const unsigned key = mx | (my << 1);       // 16-bit morton
            v = (key << 11) | (unsigned)i;             // idx in low 11 bits
        }
        keys[i] = v;
    }
    __syncthreads();

    for (int k = 2; k <= n; k <<= 1) {
        for (int j = k >> 1; j > 0; j >>= 1) {
            for (int i = t; i < n; i += 256) {
                const int ixj = i ^ j;
                if (ixj > i) {
                    const unsigned a = keys[i], b = keys[ixj];
                    const bool up = ((i & k) == 0);
                    if ((a > b) == up) { keys[i] = b; keys[ixj] = a; }
                }
            }
            __syncthreads();
        }
    }

    for (int i = t; i < N; i += 256) perm[i] = keys[i] & 0x7FFu;
}

// ---- main kernel: block per roi, wave per pooled row ----

template <int PS>
__global__ __launch_bounds__(PS * 64) void RoIPool_rows_kernel(
    const float* __restrict__ feat,   // H*W*C
    const float* __restrict__ rois,   // N*4
    const unsigned* __restrict__ perm,// sorted roi order (or null -> identity)
    float*       __restrict__ out,    // N*PS*PS*C
    int H, int W)
{
    constexpr int C4 = 64;            // C = 256 floats = 64 float4; lane==chunk
    int roi;
    if (perm) {
        // chunked XCD mapping: bid%8 = XCD; each XCD gets a contiguous run of
        // the spatially-sorted roi list. Host guards gridDim.x % 8 == 0.
        const int per_xcd = gridDim.x >> 3;
        const int s = (blockIdx.x & 7) * per_xcd + (blockIdx.x >> 3);
        roi = (int)perm[s];
    } else {
        roi = blockIdx.x;
    }
    const int py   = threadIdx.x >> 6;   // wave id == pooled row
    const int lane = threadIdx.x & 63;

    // uniform index -> scalar loads
    const float4 r = reinterpret_cast<const float4*>(rois)[roi];
    const int x = (int)r.x;   // astype(int32) == trunc; values are >= 0
    const int y = (int)r.y;
    const int w = (int)r.z;
    const int h = (int)r.w;

    // match reference fp32 math exactly
    const float sy = (float)h / (float)PS;
    const float sx = (float)w / (float)PS;

    const float src_y = (float)py * sy;
    const int   y0    = (int)floorf(src_y);
    const float wy    = src_y - (float)y0;
    const float omwy  = 1.0f - wy;
    const int gy0 = min(max(y + min(max(y0,     0), h - 1), 0), H - 1);
    const int gy1 = min(max(y + min(max(y0 + 1, 0), h - 1), 0), H - 1);

    const float4* __restrict__ f4 = reinterpret_cast<const float4*>(feat);

    const int rb0 = gy0 * W * C4 + lane;   // fits int: 200*200*64 = 2.56M
    const int rb1 = gy1 * W * C4 + lane;

    // compile-time-indexed (fully unrolled) -> stays in VGPRs, not scratch
    float4 v00[PS], v01[PS], v10[PS], v11[PS];
    float  wxa[PS];

#pragma unroll
    for (int px = 0; px < PS; ++px) {
        const float src_x = (float)px * sx;
        const int   x0    = (int)floorf(src_x);
        wxa[px] = src_x - (float)x0;
        const int gx0 = min(max(x + min(max(x0,     0), w - 1), 0), W - 1);
        const int gx1 = min(max(x + min(max(x0 + 1, 0), w - 1), 0), W - 1);
        v00[px] = f4[rb0 + gx0 * C4];
        v01[px] = f4[rb0 + gx1 * C4];
        v10[px] = f4[rb1 + gx0 * C4];
        v11[px] = f4[rb1 + gx1 * C4];
    }

    vfloat4* __restrict__ o4 = reinterpret_cast<vfloat4*>(out);
    const int ob = (roi * (PS * PS) + py * PS) * C4 + lane;

#pragma unroll
    for (int px = 0; px < PS; ++px) {
        const float wx   = wxa[px];
        const float omwx = 1.0f - wx;
        vfloat4 o;
        o.x = (v00[px].x * omwx + v01[px].x * wx) * omwy + (v10[px].x * omwx + v11[px].x * wx) * wy;
        o.y = (v00[px].y * omwx + v01[px].y * wx) * omwy + (v10[px].y * omwx + v11[px].y * wx) * wy;
        o.z = (v00[px].z * omwx + v01[px].z * wx) * omwy + (v10[px].z * omwx + v11[px].z * wx) * wy;
        o.w = (v00[px].w * omwx + v01[px].w * wx) * omwy + (v10[px].w * omwx + v11[px].w * wx) * wy;
        __builtin_nontemporal_store(o, o4 + ob + px * C4);
    }
}

// ---- fallback: per-cell kernel (any ps / C multiple of 4) ----

__global__ __launch_bounds__(256) void RoIPool_53575422050620_kernel(
    const float* __restrict__ feat,   // H*W*C
    const float* __restrict__ rois,   // N*4
    const int*   __restrict__ psp,    // pool_size scalar
    float*       __restrict__ out,    // n_cells*C
    int n_cells, int H, int W, int C)
{
    const int ps   = psp[0];
    const int cell = blockIdx.x * 4 + (threadIdx.x >> 6);
    if (cell >= n_cells) return;
    const int lane = threadIdx.x & 63;

    const int pp  = ps * ps;
    const int roi = cell / pp;
    const int rem = cell - roi * pp;
    const int py  = rem / ps;
    const int px  = rem - py * ps;

    const float4 r = reinterpret_cast<const float4*>(rois)[roi];
    const int x = (int)r.x;
    const int y = (int)r.y;
    const int w = (int)r.z;
    const int h = (int)r.w;

    const float sy    = (float)h / (float)ps;
    const float sx    = (float)w / (float)ps;
    const float src_y = (float)py * sy;
    const float src_x = (float)px * sx;
    const int y0 = (int)floorf(src_y);
    const int x0 = (int)floorf(src_x);
    const float wy = src_y - (float)y0;
    const float wx = src_x - (float)x0;

    const int gy0 = min(max(y + min(max(y0,     0), h - 1), 0), H - 1);
    const int gy1 = min(max(y + min(max(y0 + 1, 0), h - 1), 0), H - 1);
    const int gx0 = min(max(x + min(max(x0,     0), w - 1), 0), W - 1);
    const int gx1 = min(max(x + min(max(x0 + 1, 0), w - 1), 0), W - 1);

    const int C4 = C >> 2;
    const float4* __restrict__ f4 = reinterpret_cast<const float4*>(feat);
    float4* __restrict__ o4 = reinterpret_cast<float4*>(out);

    const size_t b00 = (size_t)(gy0 * W + gx0) * C4;
    const size_t b01 = (size_t)(gy0 * W + gx1) * C4;
    const size_t b10 = (size_t)(gy1 * W + gx0) * C4;
    const size_t b11 = (size_t)(gy1 * W + gx1) * C4;
    const size_t ob  = (size_t)cell * C4;

    const float omwx = 1.0f - wx;
    const float omwy = 1.0f - wy;

    for (int cv = lane; cv < C4; cv += 64) {
        const float4 v00 = f4[b00 + cv];
        const float4 v01 = f4[b01 + cv];
        const float4 v10 = f4[b10 + cv];
        const float4 v11 = f4[b11 + cv];
        float4 o;
        o.x = (v00.x * omwx + v01.x * wx) * omwy + (v10.x * omwx + v11.x * wx) * wy;
        o.y = (v00.y * omwx + v01.y * wx) * omwy + (v10.y * omwx + v11.y * wx) * wy;
        o.z = (v00.z * omwx + v01.z * wx) * omwy + (v10.z * omwx + v11.z * wx) * wy;
        o.w = (v00.w * omwx + v01.w * wx) * omwy + (v10.w * omwx + v11.w * wx) * wy;
        o4[ob + cv] = o;
    }
}

extern "C" void kernel_launch(void* const* d_in, const int* in_sizes, int n_in,
                              void* d_out, int out_size, void* d_ws, size_t ws_size,
                              hipStream_t stream) {
    const float* img  = (const float*)d_in[0];
    const float* rois = (const float*)d_in[1];
    const int*   psp  = (const int*)d_in[2];
    float*       out  = (float*)d_out;

    const int H = 200, W = 200, C = 256;
    const int n_cells = out_size / C;           // N * ps * ps
    const int N  = in_sizes[1] / 4;             // rois rows
    const int pp = (N > 0) ? (n_cells / N) : 0; // ps*ps
    int ps = 1;
    while (ps * ps < pp) ++ps;

    if (N > 0 && pp == 49 && ps * ps == pp && ps * ps * N == n_cells && C == 256) {
        unsigned* perm = nullptr;
        if (N <= 2048 && (N & 7) == 0 && ws_size >= (size_t)N * sizeof(unsigned)) {
            perm = (unsigned*)d_ws;
            RoIPool_sort_kernel<<<1, 256, 0, stream>>>(rois, N, perm);
        }
        RoIPool_rows_kernel<7><<<N, 7 * 64, 0, stream>>>(img, rois, perm, out, H, W);
    } else {
        const int blocks = (n_cells + 3) / 4;   // 4 cells (waves) per block
        RoIPool_53575422050620_kernel<<<blocks, 256, 0, stream>>>(
            img, rois, psp, out, n_cells, H, W, C);
    }
}

// Round 3
// 168.997 us; speedup vs baseline: 1.3475x; 1.3475x over previous
//
#include <hip/hip_runtime.h>

// RoI bilinear pooling.
// img : (1, H=200, W=200, C=256) fp32, NHWC  -> channel vectors contiguous (1 KiB)
// rois: (1, N=2000, 4) fp32 (integer-valued x,y,w,h)
// out : (1, N, ps, ps, C) fp32
//
// R3: cheap spatial binning pre-pass (replaces R2's 67us bitonic sort).
// RoIs are random in index order, so cross-roi pixel reuse (FETCH 158 MB vs
// 41 MB image) misses L2. Counting-sort roi indices into 256 Morton-ordered
// spatial bins (single block, 1024 threads, LDS histogram + scan + scatter:
// ~5 us). Main kernel uses chunked XCD mapping (bid%8 == XCD on MI355X) so
// each XCD processes a contiguous run of spatially-binned rois -> sliding
// working set per L2 is a few bins << 4 MB. Output still lands in the
// original roi slot, so within-bin atomic-arbitrary order is harmless.
//
// Main kernel (ps==7, C==256): one BLOCK per roi (7 waves), one WAVE per
// pooled row. Lane owns one float4 of the 256-channel vector. px loop fully
// unrolled -> 28 loads in flight per wave. Non-temporal output stores.

typedef float vfloat4 __attribute__((ext_vector_type(4)));

// ---- pre-pass: counting sort into 256 Morton spatial bins ----

__global__ __launch_bounds__(1024) void RoIPool_bin_kernel(
    const float* __restrict__ rois, int N, unsigned* __restrict__ perm)
{
    __shared__ unsigned cnt[256];    // histogram, then per-bin cursor
    __shared__ unsigned scan[256];   // inclusive prefix sum
    const int t = threadIdx.x;

    if (t < 256) cnt[t] = 0;
    __syncthreads();

    // N <= 2048, 1024 threads -> at most 2 rois per thread
    unsigned mybin[2];
    int      myroi[2];
    int      nmine = 0;
    for (int i = t; i < N; i += 1024) {
        const float4 r = reinterpret_cast<const float4*>(rois)[i];
        const int cx = (int)r.x + ((int)r.z >> 1);
        const int cy = (int)r.y + ((int)r.w >> 1);
        unsigned bx = (unsigned)min(max(cx >> 4, 0), 15);
        unsigned by = (unsigned)min(max(cy >> 4, 0), 15);
        bx = (bx | (bx << 2)) & 0x33u;  bx = (bx | (bx << 1)) & 0x55u;
        by = (by | (by << 2)) & 0x33u;  by = (by | (by << 1)) & 0x55u;
        const unsigned bin = bx | (by << 1);           // 8-bit Morton
        mybin[nmine] = bin;
        myroi[nmine] = i;
        ++nmine;
        atomicAdd(&cnt[bin], 1u);
    }
    __syncthreads();

    // inclusive Hillis-Steele scan over 256 bins
    if (t < 256) scan[t] = cnt[t];
    __syncthreads();
    for (int off = 1; off < 256; off <<= 1) {
        unsigned v = 0;
        if (t < 256 && t >= off) v = scan[t - off];
        __syncthreads();
        if (t < 256) scan[t] += v;
        __syncthreads();
    }

    // reset cursors, then scatter: pos = exclusive_base[bin] + cursor[bin]++
    if (t < 256) cnt[t] = 0;
    __syncthreads();
    for (int k = 0; k < nmine; ++k) {
        const unsigned bin  = mybin[k];
        const unsigned excl = (bin == 0) ? 0u : scan[bin - 1];
        const unsigned pos  = excl + atomicAdd(&cnt[bin], 1u);
        perm[pos] = (unsigned)myroi[k];
    }
}

// ---- main kernel: block per roi, wave per pooled row ----

template <int PS>
__global__ __launch_bounds__(PS * 64) void RoIPool_rows_kernel(
    const float* __restrict__ feat,   // H*W*C
    const float* __restrict__ rois,   // N*4
    const unsigned* __restrict__ perm,// binned roi order (or null -> identity)
    float*       __restrict__ out,    // N*PS*PS*C
    int H, int W)
{
    constexpr int C4 = 64;            // C = 256 floats = 64 float4; lane==chunk
    int roi;
    if (perm) {
        // chunked XCD mapping: bid%8 = XCD; each XCD gets a contiguous run of
        // the spatially-binned roi list. Host guards gridDim.x % 8 == 0.
        const int per_xcd = gridDim.x >> 3;
        const int s = (blockIdx.x & 7) * per_xcd + (blockIdx.x >> 3);
        roi = (int)perm[s];
    } else {
        roi = blockIdx.x;
    }
    const int py   = threadIdx.x >> 6;   // wave id == pooled row
    const int lane = threadIdx.x & 63;

    // uniform index -> scalar loads
    const float4 r = reinterpret_cast<const float4*>(rois)[roi];
    const int x = (int)r.x;   // astype(int32) == trunc; values are >= 0
    const int y = (int)r.y;
    const int w = (int)r.z;
    const int h = (int)r.w;

    // match reference fp32 math exactly
    const float sy = (float)h / (float)PS;
    const float sx = (float)w / (float)PS;

    const float src_y = (float)py * sy;
    const int   y0    = (int)floorf(src_y);
    const float wy    = src_y - (float)y0;
    const float omwy  = 1.0f - wy;
    const int gy0 = min(max(y + min(max(y0,     0), h - 1), 0), H - 1);
    const int gy1 = min(max(y + min(max(y0 + 1, 0), h - 1), 0), H - 1);

    const float4* __restrict__ f4 = reinterpret_cast<const float4*>(feat);

    const int rb0 = gy0 * W * C4 + lane;   // fits int: 200*200*64 = 2.56M
    const int rb1 = gy1 * W * C4 + lane;

    // compile-time-indexed (fully unrolled) -> stays in VGPRs, not scratch
    float4 v00[PS], v01[PS], v10[PS], v11[PS];
    float  wxa[PS];

#pragma unroll
    for (int px = 0; px < PS; ++px) {
        const float src_x = (float)px * sx;
        const int   x0    = (int)floorf(src_x);
        wxa[px] = src_x - (float)x0;
        const int gx0 = min(max(x + min(max(x0,     0), w - 1), 0), W - 1);
        const int gx1 = min(max(x + min(max(x0 + 1, 0), w - 1), 0), W - 1);
        v00[px] = f4[rb0 + gx0 * C4];
        v01[px] = f4[rb0 + gx1 * C4];
        v10[px] = f4[rb1 + gx0 * C4];
        v11[px] = f4[rb1 + gx1 * C4];
    }

    vfloat4* __restrict__ o4 = reinterpret_cast<vfloat4*>(out);
    const int ob = (roi * (PS * PS) + py * PS) * C4 + lane;

#pragma unroll
    for (int px = 0; px < PS; ++px) {
        const float wx   = wxa[px];
        const float omwx = 1.0f - wx;
        vfloat4 o;
        o.x = (v00[px].x * omwx + v01[px].x * wx) * omwy + (v10[px].x * omwx + v11[px].x * wx) * wy;
        o.y = (v00[px].y * omwx + v01[px].y * wx) * omwy + (v10[px].y * omwx + v11[px].y * wx) * wy;
        o.z = (v00[px].z * omwx + v01[px].z * wx) * omwy + (v10[px].z * omwx + v11[px].z * wx) * wy;
        o.w = (v00[px].w * omwx + v01[px].w * wx) * omwy + (v10[px].w * omwx + v11[px].w * wx) * wy;
        __builtin_nontemporal_store(o, o4 + ob + px * C4);
    }
}

// ---- fallback: per-cell kernel (any ps / C multiple of 4) ----

__global__ __launch_bounds__(256) void RoIPool_53575422050620_kernel(
    const float* __restrict__ feat,   // H*W*C
    const float* __restrict__ rois,   // N*4
    const int*   __restrict__ psp,    // pool_size scalar
    float*       __restrict__ out,    // n_cells*C
    int n_cells, int H, int W, int C)
{
    const int ps   = psp[0];
    const int cell = blockIdx.x * 4 + (threadIdx.x >> 6);
    if (cell >= n_cells) return;
    const int lane = threadIdx.x & 63;

    const int pp  = ps * ps;
    const int roi = cell / pp;
    const int rem = cell - roi * pp;
    const int py  = rem / ps;
    const int px  = rem - py * ps;

    const float4 r = reinterpret_cast<const float4*>(rois)[roi];
    const int x = (int)r.x;
    const int y = (int)r.y;
    const int w = (int)r.z;
    const int h = (int)r.w;

    const float sy    = (float)h / (float)ps;
    const float sx    = (float)w / (float)ps;
    const float src_y = (float)py * sy;
    const float src_x = (float)px * sx;
    const int y0 = (int)floorf(src_y);
    const int x0 = (int)floorf(src_x);
    const float wy = src_y - (float)y0;
    const float wx = src_x - (float)x0;

    const int gy0 = min(max(y + min(max(y0,     0), h - 1), 0), H - 1);
    const int gy1 = min(max(y + min(max(y0 + 1, 0), h - 1), 0), H - 1);
    const int gx0 = min(max(x + min(max(x0,     0), w - 1), 0), W - 1);
    const int gx1 = min(max(x + min(max(x0 + 1, 0), w - 1), 0), W - 1);

    const int C4 = C >> 2;
    const float4* __restrict__ f4 = reinterpret_cast<const float4*>(feat);
    float4* __restrict__ o4 = reinterpret_cast<float4*>(out);

    const size_t b00 = (size_t)(gy0 * W + gx0) * C4;
    const size_t b01 = (size_t)(gy0 * W + gx1) * C4;
    const size_t b10 = (size_t)(gy1 * W + gx0) * C4;
    const size_t b11 = (size_t)(gy1 * W + gx1) * C4;
    const size_t ob  = (size_t)cell * C4;

    const float omwx = 1.0f - wx;
    const float omwy = 1.0f - wy;

    for (int cv = lane; cv < C4; cv += 64) {
        const float4 v00 = f4[b00 + cv];
        const float4 v01 = f4[b01 + cv];
        const float4 v10 = f4[b10 + cv];
        const float4 v11 = f4[b11 + cv];
        float4 o;
        o.x = (v00.x * omwx + v01.x * wx) * omwy + (v10.x * omwx + v11.x * wx) * wy;
        o.y = (v00.y * omwx + v01.y * wx) * omwy + (v10.y * omwx + v11.y * wx) * wy;
        o.z = (v00.z * omwx + v01.z * wx) * omwy + (v10.z * omwx + v11.z * wx) * wy;
        o.w = (v00.w * omwx + v01.w * wx) * omwy + (v10.w * omwx + v11.w * wx) * wy;
        o4[ob + cv] = o;
    }
}

extern "C" void kernel_launch(void* const* d_in, const int* in_sizes, int n_in,
                              void* d_out, int out_size, void* d_ws, size_t ws_size,
                              hipStream_t stream) {
    const float* img  = (const float*)d_in[0];
    const float* rois = (const float*)d_in[1];
    const int*   psp  = (const int*)d_in[2];
    float*       out  = (float*)d_out;

    const int H = 200, W = 200, C = 256;
    const int n_cells = out_size / C;           // N * ps * ps
    const int N  = in_sizes[1] / 4;             // rois rows
    const int pp = (N > 0) ? (n_cells / N) : 0; // ps*ps
    int ps = 1;
    while (ps * ps < pp) ++ps;

    if (N > 0 && pp == 49 && ps * ps == pp && ps * ps * N == n_cells && C == 256) {
        unsigned* perm = nullptr;
        if (N <= 2048 && (N & 7) == 0 && ws_size >= (size_t)N * sizeof(unsigned)) {
            perm = (unsigned*)d_ws;
            RoIPool_bin_kernel<<<1, 1024, 0, stream>>>(rois, N, perm);
        }
        RoIPool_rows_kernel<7><<<N, 7 * 64, 0, stream>>>(img, rois, perm, out, H, W);
    } else {
        const int blocks = (n_cells + 3) / 4;   // 4 cells (waves) per block
        RoIPool_53575422050620_kernel<<<blocks, 256, 0, stream>>>(
            img, rois, psp, out, n_cells, H, W, C);
    }
}

// Round 4
// 167.099 us; speedup vs baseline: 1.3628x; 1.0114x over previous
//
#include <hip/hip_runtime.h>

// RoI bilinear pooling.
// img : (1, H=200, W=200, C=256) fp32, NHWC  -> channel vectors contiguous (1 KiB)
// rois: (1, N=2000, 4) fp32 (integer-valued x,y,w,h)
// out : (1, N, ps, ps, C) fp32
//
// R4: 4x finer spatial binning (1024 Morton bins of 8-px cells, ~2 rois/bin)
// to tighten each XCD-L2's sliding working set. RoIs are random in index
// order; cross-roi pixel reuse only pays if rois that touch the same pixels
// run close in time on the same XCD. Counting-sort pre-pass (single block,
// 1024 threads: LDS histogram -> Hillis-Steele scan -> atomic scatter).
// Main kernel uses chunked XCD mapping (bid%8 == XCD on MI355X) so each XCD
// processes a contiguous run of the Morton-ordered roi list. Output still
// lands in the original roi slot, so within-bin arbitrary order is harmless.
//
// Main kernel (ps==7, C==256): one BLOCK per roi (7 waves), one WAVE per
// pooled row. Lane owns one float4 of the 256-channel vector. px loop fully
// unrolled. Non-temporal output stores (write-once, keep image in L2/L3).

typedef float vfloat4 __attribute__((ext_vector_type(4)));

// ---- pre-pass: counting sort into 1024 Morton spatial bins (8-px cells) ----

__global__ __launch_bounds__(1024) void RoIPool_bin_kernel(
    const float* __restrict__ rois, int N, unsigned* __restrict__ perm)
{
    constexpr int NB = 1024;         // 32x32 Morton space (25x25 cells used)
    __shared__ unsigned cnt[NB];     // histogram, then per-bin cursor
    __shared__ unsigned scan[NB];    // inclusive prefix sum
    const int t = threadIdx.x;

    cnt[t] = 0;
    __syncthreads();

    // N <= 2048, 1024 threads -> at most 2 rois per thread
    unsigned mybin[2];
    int      myroi[2];
    int      nmine = 0;
    for (int i = t; i < N; i += 1024) {
        const float4 r = reinterpret_cast<const float4*>(rois)[i];
        const int cx = (int)r.x + ((int)r.z >> 1);   // roi center, >= 0
        const int cy = (int)r.y + ((int)r.w >> 1);
        unsigned bx = (unsigned)min(max(cx >> 3, 0), 31);  // 8-px cells
        unsigned by = (unsigned)min(max(cy >> 3, 0), 31);
        // part1by1 (ok for any 8-bit value)
        bx = (bx | (bx << 4)) & 0x0F0Fu;  bx = (bx | (bx << 2)) & 0x3333u;
        bx = (bx | (bx << 1)) & 0x5555u;
        by = (by | (by << 4)) & 0x0F0Fu;  by = (by | (by << 2)) & 0x3333u;
        by = (by | (by << 1)) & 0x5555u;
        const unsigned bin = bx | (by << 1);           // 10-bit Morton
        mybin[nmine] = bin;
        myroi[nmine] = i;
        ++nmine;
        atomicAdd(&cnt[bin], 1u);
    }
    __syncthreads();

    // inclusive Hillis-Steele scan over 1024 bins (one bin per thread)
    scan[t] = cnt[t];
    __syncthreads();
    for (int off = 1; off < NB; off <<= 1) {
        unsigned v = 0;
        if (t >= off) v = scan[t - off];
        __syncthreads();
        scan[t] += v;
        __syncthreads();
    }

    // reset cursors, then scatter: pos = exclusive_base[bin] + cursor[bin]++
    cnt[t] = 0;
    __syncthreads();
    for (int k = 0; k < nmine; ++k) {
        const unsigned bin  = mybin[k];
        const unsigned excl = (bin == 0) ? 0u : scan[bin - 1];
        const unsigned pos  = excl + atomicAdd(&cnt[bin], 1u);
        perm[pos] = (unsigned)myroi[k];
    }
}

// ---- main kernel: block per roi, wave per pooled row ----

template <int PS>
__global__ __launch_bounds__(PS * 64) void RoIPool_rows_kernel(
    const float* __restrict__ feat,   // H*W*C
    const float* __restrict__ rois,   // N*4
    const unsigned* __restrict__ perm,// binned roi order (or null -> identity)
    float*       __restrict__ out,    // N*PS*PS*C
    int H, int W)
{
    constexpr int C4 = 64;            // C = 256 floats = 64 float4; lane==chunk
    int roi;
    if (perm) {
        // chunked XCD mapping: bid%8 = XCD; each XCD gets a contiguous run of
        // the Morton-ordered roi list. Host guards gridDim.x % 8 == 0.
        const int per_xcd = gridDim.x >> 3;
        const int s = (blockIdx.x & 7) * per_xcd + (blockIdx.x >> 3);
        roi = (int)perm[s];
    } else {
        roi = blockIdx.x;
    }
    const int py   = threadIdx.x >> 6;   // wave id == pooled row
    const int lane = threadIdx.x & 63;

    // uniform index -> scalar loads
    const float4 r = reinterpret_cast<const float4*>(rois)[roi];
    const int x = (int)r.x;   // astype(int32) == trunc; values are >= 0
    const int y = (int)r.y;
    const int w = (int)r.z;
    const int h = (int)r.w;

    // match reference fp32 math exactly
    const float sy = (float)h / (float)PS;
    const float sx = (float)w / (float)PS;

    const float src_y = (float)py * sy;
    const int   y0    = (int)floorf(src_y);
    const float wy    = src_y - (float)y0;
    const float omwy  = 1.0f - wy;
    const int gy0 = min(max(y + min(max(y0,     0), h - 1), 0), H - 1);
    const int gy1 = min(max(y + min(max(y0 + 1, 0), h - 1), 0), H - 1);

    const float4* __restrict__ f4 = reinterpret_cast<const float4*>(feat);

    const int rb0 = gy0 * W * C4 + lane;   // fits int: 200*200*64 = 2.56M
    const int rb1 = gy1 * W * C4 + lane;

    // compile-time-indexed (fully unrolled) -> stays in VGPRs, not scratch
    float4 v00[PS], v01[PS], v10[PS], v11[PS];
    float  wxa[PS];

#pragma unroll
    for (int px = 0; px < PS; ++px) {
        const float src_x = (float)px * sx;
        const int   x0    = (int)floorf(src_x);
        wxa[px] = src_x - (float)x0;
        const int gx0 = min(max(x + min(max(x0,     0), w - 1), 0), W - 1);
        const int gx1 = min(max(x + min(max(x0 + 1, 0), w - 1), 0), W - 1);
        v00[px] = f4[rb0 + gx0 * C4];
        v01[px] = f4[rb0 + gx1 * C4];
        v10[px] = f4[rb1 + gx0 * C4];
        v11[px] = f4[rb1 + gx1 * C4];
    }

    vfloat4* __restrict__ o4 = reinterpret_cast<vfloat4*>(out);
    const int ob = (roi * (PS * PS) + py * PS) * C4 + lane;

#pragma unroll
    for (int px = 0; px < PS; ++px) {
        const float wx   = wxa[px];
        const float omwx = 1.0f - wx;
        vfloat4 o;
        o.x = (v00[px].x * omwx + v01[px].x * wx) * omwy + (v10[px].x * omwx + v11[px].x * wx) * wy;
        o.y = (v00[px].y * omwx + v01[px].y * wx) * omwy + (v10[px].y * omwx + v11[px].y * wx) * wy;
        o.z = (v00[px].z * omwx + v01[px].z * wx) * omwy + (v10[px].z * omwx + v11[px].z * wx) * wy;
        o.w = (v00[px].w * omwx + v01[px].w * wx) * omwy + (v10[px].w * omwx + v11[px].w * wx) * wy;
        __builtin_nontemporal_store(o, o4 + ob + px * C4);
    }
}

// ---- fallback: per-cell kernel (any ps / C multiple of 4) ----

__global__ __launch_bounds__(256) void RoIPool_53575422050620_kernel(
    const float* __restrict__ feat,   // H*W*C
    const float* __restrict__ rois,   // N*4
    const int*   __restrict__ psp,    // pool_size scalar
    float*       __restrict__ out,    // n_cells*C
    int n_cells, int H, int W, int C)
{
    const int ps   = psp[0];
    const int cell = blockIdx.x * 4 + (threadIdx.x >> 6);
    if (cell >= n_cells) return;
    const int lane = threadIdx.x & 63;

    const int pp  = ps * ps;
    const int roi = cell / pp;
    const int rem = cell - roi * pp;
    const int py  = rem / ps;
    const int px  = rem - py * ps;

    const float4 r = reinterpret_cast<const float4*>(rois)[roi];
    const int x = (int)r.x;
    const int y = (int)r.y;
    const int w = (int)r.z;
    const int h = (int)r.w;

    const float sy    = (float)h / (float)ps;
    const float sx    = (float)w / (float)ps;
    const float src_y = (float)py * sy;
    const float src_x = (float)px * sx;
    const int y0 = (int)floorf(src_y);
    const int x0 = (int)floorf(src_x);
    const float wy = src_y - (float)y0;
    const float wx = src_x - (float)x0;

    const int gy0 = min(max(y + min(max(y0,     0), h - 1), 0), H - 1);
    const int gy1 = min(max(y + min(max(y0 + 1, 0), h - 1), 0), H - 1);
    const int gx0 = min(max(x + min(max(x0,     0), w - 1), 0), W - 1);
    const int gx1 = min(max(x + min(max(x0 + 1, 0), w - 1), 0), W - 1);

    const int C4 = C >> 2;
    const float4* __restrict__ f4 = reinterpret_cast<const float4*>(feat);
    float4* __restrict__ o4 = reinterpret_cast<float4*>(out);

    const size_t b00 = (size_t)(gy0 * W + gx0) * C4;
    const size_t b01 = (size_t)(gy0 * W + gx1) * C4;
    const size_t b10 = (size_t)(gy1 * W + gx0) * C4;
    const size_t b11 = (size_t)(gy1 * W + gx1) * C4;
    const size_t ob  = (size_t)cell * C4;

    const float omwx = 1.0f - wx;
    const float omwy = 1.0f - wy;

    for (int cv = lane; cv < C4; cv += 64) {
        const float4 v00 = f4[b00 + cv];
        const float4 v01 = f4[b01 + cv];
        const float4 v10 = f4[b10 + cv];
        const float4 v11 = f4[b11 + cv];
        float4 o;
        o.x = (v00.x * omwx + v01.x * wx) * omwy + (v10.x * omwx + v11.x * wx) * wy;
        o.y = (v00.y * omwx + v01.y * wx) * omwy + (v10.y * omwx + v11.y * wx) * wy;
        o.z = (v00.z * omwx + v01.z * wx) * omwy + (v10.z * omwx + v11.z * wx) * wy;
        o.w = (v00.w * omwx + v01.w * wx) * omwy + (v10.w * omwx + v11.w * wx) * wy;
        o4[ob + cv] = o;
    }
}

extern "C" void kernel_launch(void* const* d_in, const int* in_sizes, int n_in,
                              void* d_out, int out_size, void* d_ws, size_t ws_size,
                              hipStream_t stream) {
    const float* img  = (const float*)d_in[0];
    const float* rois = (const float*)d_in[1];
    const int*   psp  = (const int*)d_in[2];
    float*       out  = (float*)d_out;

    const int H = 200, W = 200, C = 256;
    const int n_cells = out_size / C;           // N * ps * ps
    const int N  = in_sizes[1] / 4;             // rois rows
    const int pp = (N > 0) ? (n_cells / N) : 0; // ps*ps
    int ps = 1;
    while (ps * ps < pp) ++ps;

    if (N > 0 && pp == 49 && ps * ps == pp && ps * ps * N == n_cells && C == 256) {
        unsigned* perm = nullptr;
        if (N <= 2048 && (N & 7) == 0 && ws_size >= (size_t)N * sizeof(unsigned)) {
            perm = (unsigned*)d_ws;
            RoIPool_bin_kernel<<<1, 1024, 0, stream>>>(rois, N, perm);
        }
        RoIPool_rows_kernel<7><<<N, 7 * 64, 0, stream>>>(img, rois, perm, out, H, W);
    } else {
        const int blocks = (n_cells + 3) / 4;   // 4 cells (waves) per block
        RoIPool_53575422050620_kernel<<<blocks, 256, 0, stream>>>(
            img, rois, psp, out, n_cells, H, W, C);
    }
}